// Round 14
// baseline (1778.352 us; speedup 1.0000x reference)
//
#include <hip/hip_runtime.h>
#include <stdint.h>

// Problem constants (fixed by the reference)
#define TOKENS 8192
#define D_IN   1024
#define NEXP   8
#define D_OUT  1024
#define HDIM   2048

typedef __bf16 bf16x8 __attribute__((ext_vector_type(8)));
typedef __bf16 bf16x4 __attribute__((ext_vector_type(4)));
typedef float  f32x4  __attribute__((ext_vector_type(4)));

// ---------------------------------------------------------------------------
__device__ __forceinline__ void gload16(const void* g, void* l) {
  __builtin_amdgcn_global_load_lds(
      (const __attribute__((address_space(1))) void*)g,
      (__attribute__((address_space(3))) void*)l,
      16, 0, 0);
}

template <int N>
__device__ __forceinline__ void waitv() {
  if constexpr (N == 0)      asm volatile("s_waitcnt vmcnt(0)" ::: "memory");
  else if constexpr (N == 1) asm volatile("s_waitcnt vmcnt(1)" ::: "memory");
  else if constexpr (N == 2) asm volatile("s_waitcnt vmcnt(2)" ::: "memory");
  else if constexpr (N == 3) asm volatile("s_waitcnt vmcnt(3)" ::: "memory");
  else if constexpr (N == 4) asm volatile("s_waitcnt vmcnt(4)" ::: "memory");
  else if constexpr (N == 6) asm volatile("s_waitcnt vmcnt(6)" ::: "memory");
  else if constexpr (N == 8) asm volatile("s_waitcnt vmcnt(8)" ::: "memory");
  else static_assert(N <= 8, "unsupported vmcnt");
}

// ---------------------------------------------------------------------------
// Fused gating + x->bf16 conversion. One wave per token.
__global__ void gate_cvt_kernel(const float* __restrict__ x,
                                const float* __restrict__ Wg,
                                const float* __restrict__ bg,
                                float* __restrict__ gates,
                                __bf16* __restrict__ xb) {
  const int lane = threadIdx.x & 63;
  const int n = blockIdx.x * 4 + (threadIdx.x >> 6);
  float acc[NEXP];
#pragma unroll
  for (int e = 0; e < NEXP; ++e) acc[e] = 0.f;
  const float* xr = x + (size_t)n * D_IN;
  __bf16* xo = xb + (size_t)n * D_IN;
#pragma unroll 4
  for (int d0 = 0; d0 < D_IN; d0 += 64) {
    const int d = d0 + lane;
    float xv = xr[d];
    xo[d] = (__bf16)xv;
    const float* wr = Wg + d * NEXP;
#pragma unroll
    for (int e = 0; e < NEXP; ++e) acc[e] += xv * wr[e];
  }
#pragma unroll
  for (int e = 0; e < NEXP; ++e) {
    float v = acc[e];
#pragma unroll
    for (int off = 32; off > 0; off >>= 1) v += __shfl_down(v, off);
    acc[e] = v;
  }
  if (lane == 0) {
    float mx = -1e30f;
#pragma unroll
    for (int e = 0; e < NEXP; ++e) { acc[e] += bg[e]; mx = fmaxf(mx, acc[e]); }
    float s = 0.f;
#pragma unroll
    for (int e = 0; e < NEXP; ++e) { acc[e] = expf(acc[e] - mx); s += acc[e]; }
    float inv = 1.f / s;
#pragma unroll
    for (int e = 0; e < NEXP; ++e) gates[n * NEXP + e] = acc[e] * inv;
  }
}

// ---------------------------------------------------------------------------
// Transpose-convert: f32 W[e][k][n] -> bf16 Wt[slice = e/EPG][n][(e%EPG)*K + k]
__global__ void transpose_cvt_kernel(const float* __restrict__ W,
                                     __bf16* __restrict__ Wt,
                                     int K, int N, int EPG) {
  __shared__ float tile[32][33];
  const int e = blockIdx.z;
  const int ldo = EPG * K;
  const float* Win = W + (size_t)e * K * N;
  __bf16* Wout = Wt + (size_t)(e / EPG) * N * ldo + (size_t)(e % EPG) * K;
  const int n0 = blockIdx.x * 32;
  const int k0 = blockIdx.y * 32;
  const int tx = threadIdx.x & 31;
  const int ty = threadIdx.x >> 5;
#pragma unroll
  for (int r = ty; r < 32; r += 8)
    tile[r][tx] = Win[(size_t)(k0 + r) * N + n0 + tx];
  __syncthreads();
#pragma unroll
  for (int r = ty; r < 32; r += 8)
    Wout[(size_t)(n0 + r) * ldo + k0 + tx] = (__bf16)tile[tx][r];
}

// ---------------------------------------------------------------------------
// Final merge: out[n][f] += (use_acc1 ? acc1[n][f] : 0) + sum_e g[n][e]*b2[e][f]
__global__ void merge_kernel(float* __restrict__ out,
                             const float* __restrict__ acc1,
                             const float* __restrict__ gates,
                             const float* __restrict__ b2,
                             int use_acc1) {
  const int idx = blockIdx.x * 256 + threadIdx.x;   // over TOKENS*D_OUT/4
  const int n = idx >> 8;
  const int fb = idx & 255;
  float4 o = ((const float4*)out)[idx];
  if (use_acc1) {
    float4 a = ((const float4*)acc1)[idx];
    o.x += a.x; o.y += a.y; o.z += a.z; o.w += a.w;
  }
  const float* g = gates + (size_t)n * NEXP;
#pragma unroll
  for (int e = 0; e < NEXP; ++e) {
    const float ge = g[e];
    float4 b = ((const float4*)(b2 + (size_t)e * D_OUT))[fb];
    o.x += ge * b.x; o.y += ge * b.y; o.z += ge * b.z; o.w += ge * b.w;
  }
  ((float4*)out)[idx] = o;
}

// ---------------------------------------------------------------------------
// Rotating GEMM: D = A[M][K]*B[N][K]^T, bf16, f32 accum. BK=64, XOR swizzle
// (row&7)<<4 on LDS layout. Per-wave tile 128x64.
//
// DBUF=1 (R8-verified, gload_lds staging): one slot, 4 phases/K-tile,
//   quarters restaged in-place; counted vmcnt.
// DBUF=3 (NEW, reg-staged COALESCED): global_load_dwordx4 with LINEAR lane
//   addresses (full 128B coalescing — the pre-swizzled gload_lds source was
//   scattering 16B requests and pinning the fetch path at ~870 GB/s), then
//   ds_write_b128 to the swizzled LDS offsets (same layout as before; read
//   side unchanged). 2 slots, 2 reg sets (compile-time parity: loop body
//   processes 2 K-tiles). Per K-tile: {rd A0+all-B; issue loads t+2;
//   lgkm0; 32-MFMA | rd A1; vmcnt(8) [tile t+1 regs done, t+2 in flight];
//   ds_write tile t+1 -> other slot; lgkm0; 32-MFMA; barrier}. ONE barrier
//   per K-tile. Waits never 0 mid-loop. Race-free: write-slot != read-slot;
//   lgkm0 drains ds_writes before the barrier that publishes them.
// z-dim: A += z*AZ, B += z*BZ.
// EPI 0 (GEMM1): Hout[row][z*OCZ+col] = bf16(relu(D+b1[e0+z][col])*g[row][e0+z])
// EPI 3 (GEMM2): F = (z ? F1 : F0); F[row][col] (first ? = : +=) D.
template <int NT, int BM, int BN, int WM, int WN, int EPI, int DBUF>
__global__ __launch_bounds__(NT, 2)
void moe_gemm(const __bf16* __restrict__ A, size_t AZ,
              const __bf16* __restrict__ B, size_t BZ,
              const float* __restrict__ b1g,
              const float* __restrict__ gates,
              int e0,
              __bf16* __restrict__ Hout, size_t HZ, int OCZ, int ldo,
              float* __restrict__ F0, float* __restrict__ F1,
              int first, int M, int N, int K) {
  constexpr int RM = BM / WM, RN = BN / WN;
  constexpr int FM = RM / 16, FN = RN / 16;
  constexpr int HM = FM / 2,  HN = FN / 2;
  constexpr int LA = BM * 4 / NT;       // gloads/thread per A-half
  constexpr int LB = BN * 4 / NT;       // gloads/thread per B-half
  constexpr int TILE = 2 * LA + 2 * LB; // loads/thread per K-tile (=8 @256²)
  constexpr int AELEM = BM * 64;        // A region elems per slot
  constexpr int SLOT  = (BM + BN) * 64; // elems per slot
  constexpr int NSLOT = (DBUF == 1) ? 1 : 2;
  static_assert(HM * HN * 2 == 16, "want 16-MFMA quadrant clusters");
  __shared__ alignas(16) __bf16 lds[NSLOT * SLOT];

  const int tid  = threadIdx.x;
  const int lane = tid & 63;
  const int wave = tid >> 6;
  const int wr   = wave / WN;
  const int wc   = wave % WN;
  const int lrow = lane & 15;
  const int khi  = lane >> 4;
  const int sx   = (lrow & 7) << 3;     // read-side swizzle (elements)
  const int bz   = blockIdx.z;

  A += (size_t)bz * AZ;
  B += (size_t)bz * BZ;

  // XCD-aware bijective block swizzle (per-z nwg divisible by 8)
  const int Gx   = gridDim.x;
  const int nwg  = Gx * gridDim.y;
  const int orig = blockIdx.y * Gx + blockIdx.x;
  const int wgid = (orig & 7) * (nwg >> 3) + (orig >> 3);
  const int bn0  = (wgid % Gx) * BN;
  const int bm0  = (wgid / Gx) * BM;

  f32x4 acc[FM][FN];
#pragma unroll
  for (int m = 0; m < FM; ++m)
#pragma unroll
    for (int n = 0; n < FN; ++n) acc[m][n] = f32x4{0.f, 0.f, 0.f, 0.f};

  bf16x8 af[HM][2];       // current mq-half A fragments
  bf16x8 bf[2][HN][2];    // B fragments, cached across the K-tile

  // Fragment rows of half mq live in staged block-half mq.
  auto rdA = [&](const __bf16* As, int mq) {
#pragma unroll
    for (int mi = 0; mi < HM; ++mi)
#pragma unroll
      for (int kk = 0; kk < 2; ++kk)
        af[mi][kk] = *(const bf16x8*)
            &As[(size_t)(mq * (BM / 2) + wr * (RM / 2) + mi * 16 + lrow) * 64 +
                ((kk * 32 + khi * 8) ^ sx)];
  };
  auto rdB = [&](const __bf16* Bs, int nq) {
#pragma unroll
    for (int ni = 0; ni < HN; ++ni)
#pragma unroll
      for (int kk = 0; kk < 2; ++kk)
        bf[nq][ni][kk] = *(const bf16x8*)
            &Bs[(size_t)(nq * (BN / 2) + wc * (RN / 2) + ni * 16 + lrow) * 64 +
                ((kk * 32 + khi * 8) ^ sx)];
  };
  // 16-MFMA quadrant cluster (DBUF=1)
  auto cluster = [&](int mq, int nq) {
    __builtin_amdgcn_s_setprio(1);
#pragma unroll
    for (int kk = 0; kk < 2; ++kk)
#pragma unroll
      for (int mi = 0; mi < HM; ++mi)
#pragma unroll
        for (int ni = 0; ni < HN; ++ni)
          acc[mq * HM + mi][nq * HN + ni] =
              __builtin_amdgcn_mfma_f32_16x16x32_bf16(
                  af[mi][kk], bf[nq][ni][kk], acc[mq * HM + mi][nq * HN + ni],
                  0, 0, 0);
    __builtin_amdgcn_s_setprio(0);
  };
  // 32-MFMA half cluster: m-half mq x ALL n (DBUF=3)
  auto cluster_h = [&](int mq) {
    __builtin_amdgcn_s_setprio(1);
#pragma unroll
    for (int kk = 0; kk < 2; ++kk)
#pragma unroll
      for (int mi = 0; mi < HM; ++mi)
#pragma unroll
        for (int nq = 0; nq < 2; ++nq)
#pragma unroll
          for (int ni = 0; ni < HN; ++ni)
            acc[mq * HM + mi][nq * HN + ni] =
                __builtin_amdgcn_mfma_f32_16x16x32_bf16(
                    af[mi][kk], bf[nq][ni][kk], acc[mq * HM + mi][nq * HN + ni],
                    0, 0, 0);
    __builtin_amdgcn_s_setprio(0);
  };

#define BAR()   asm volatile("s_barrier" ::: "memory")
#define LGKM0() do { asm volatile("s_waitcnt lgkmcnt(0)" ::: "memory"); \
                     __builtin_amdgcn_sched_barrier(0); } while (0)

  const int nk = K >> 6;

  if constexpr (DBUF == 1) {
    // ---- R8-verified single-slot 4-phase schedule (gload_lds staging) ----
    const __bf16* srcA[2][LA];
    const __bf16* srcB[2][LB];
#pragma unroll
    for (int q = 0; q < 2; ++q) {
#pragma unroll
      for (int j = 0; j < LA; ++j) {
        int o   = q * (BM * 64) + j * (NT * 16) + tid * 16;
        int row = o >> 7;
        int cb  = (o & 127) ^ ((row & 7) << 4);
        srcA[q][j] = A + (size_t)(bm0 + row) * K + (cb >> 1);
      }
#pragma unroll
      for (int j = 0; j < LB; ++j) {
        int o   = q * (BN * 64) + j * (NT * 16) + tid * 16;
        int row = o >> 7;
        int cb  = (o & 127) ^ ((row & 7) << 4);
        srcB[q][j] = B + (size_t)(bn0 + row) * K + (cb >> 1);
      }
    }
    auto stageA = [&](int kt, int q) {
#pragma unroll
      for (int j = 0; j < LA; ++j)
        gload16(srcA[q][j] + (size_t)kt * 64,
                lds + q * (BM * 32) + j * (NT * 8) + wave * 512);
    };
    auto stageB = [&](int kt, int q) {
#pragma unroll
      for (int j = 0; j < LB; ++j)
        gload16(srcB[q][j] + (size_t)kt * 64,
                lds + AELEM + q * (BN * 32) + j * (NT * 8) + wave * 512);
    };

    stageA(0, 0); stageB(0, 0); stageB(0, 1);
    waitv<LB>();
    BAR();
    for (int t = 0; t < nk; ++t) {
      const bool pf = (t + 1 < nk);
      rdA(lds, 0); rdB(lds + AELEM, 0);
      stageA(t, 1);
      BAR(); LGKM0();
      cluster(0, 0);
      waitv<LA>();
      BAR();
      rdB(lds + AELEM, 1);
      if (pf) stageA(t + 1, 0);
      BAR(); LGKM0();
      cluster(0, 1);
      if (pf) waitv<LA>(); else waitv<0>();
      BAR();
      rdA(lds, 1);
      if (pf) stageB(t + 1, 0);
      BAR(); LGKM0();
      cluster(1, 0);
      BAR();
      if (pf) stageB(t + 1, 1);
      BAR();
      cluster(1, 1);
      if (pf) waitv<LB>();
      BAR();
    }
  } else {
    // ---- DBUF=3: reg-staged coalesced pipeline ----
    static_assert(TILE == 8, "reg-staged path sized for 256x256 tiles");
    // Linear global sources (coalesced) + swizzled LDS dest byte offsets.
    const __bf16* srcLin[8];
    int dstSwz[8];
#pragma unroll
    for (int i = 0; i < 8; ++i) {
      int o    = i * (NT * 16) + tid * 16;
      bool isA = (o < BM * 128);
      int oo   = isA ? o : (o - BM * 128);
      int row  = oo >> 7;
      int colb = oo & 127;
      srcLin[i] = (isA ? A + (size_t)(bm0 + row) * K
                       : B + (size_t)(bn0 + row) * K) + (colb >> 1);
      dstSwz[i] = (isA ? 0 : BM * 128) +
                  ((oo & ~127) | (colb ^ ((row & 7) << 4)));
    }
    auto issue = [&](int kt, float4* R) {
#pragma unroll
      for (int i = 0; i < 8; ++i)
        R[i] = *reinterpret_cast<const float4*>(srcLin[i] + (size_t)kt * 64);
    };
    auto wstage = [&](const float4* R, int s) {
      char* base = (char*)lds + (size_t)s * (SLOT * 2);
#pragma unroll
      for (int i = 0; i < 8; ++i)
        *reinterpret_cast<float4*>(base + dstSwz[i]) = R[i];
    };

    float4 R0[8], R1[8];
    issue(0, R0); issue(1, R1);
    waitv<8>();          // tile 0 regs done; tile 1 in flight
    wstage(R0, 0);
    LGKM0();
    BAR();               // slot 0 visible

    const int half = nk >> 1;   // nk even (K multiple of 128)
    for (int tt = 0; tt < half; ++tt) {
      {  // ---- t0 = 2tt : read slot 0 ; write tile t0+1 (R1) -> slot 1
        const int t = 2 * tt;
        const __bf16* As = lds;
        const __bf16* Bs = lds + AELEM;
        const bool pf2 = (t + 2 < nk);
        rdA(As, 0); rdB(Bs, 0); rdB(Bs, 1);
        if (pf2) issue(t + 2, R0);
        LGKM0();
        cluster_h(0);
        rdA(As, 1);
        if (pf2) waitv<8>(); else waitv<0>();   // tile t+1 regs landed
        wstage(R1, 1);
        LGKM0();
        cluster_h(1);
        BAR();
      }
      {  // ---- t1 = 2tt+1 : read slot 1 ; write tile t1+1 (R0) -> slot 0
        const int t = 2 * tt + 1;
        const __bf16* As = lds + SLOT;
        const __bf16* Bs = As + AELEM;
        const bool pf1 = (t + 1 < nk);
        const bool pf2 = (t + 2 < nk);
        rdA(As, 0); rdB(Bs, 0); rdB(Bs, 1);
        if (pf2) issue(t + 2, R1);
        LGKM0();
        cluster_h(0);
        rdA(As, 1);
        if (pf1) {
          if (pf2) waitv<8>(); else waitv<0>();
          wstage(R0, 0);
        }
        LGKM0();
        cluster_h(1);
        BAR();
      }
    }
  }

#undef BAR
#undef LGKM0

  // Epilogue. C/D frag: col = lane&15, row = (lane>>4)*4 + reg  [HW-verified]
  const float* bias = (EPI == 0) ? b1g + (size_t)(e0 + bz) * HDIM : nullptr;
  const int ecol = e0 + bz;
  __bf16* Hp = (EPI == 0) ? Hout + (size_t)bz * HZ + (size_t)bz * OCZ : nullptr;
  float* F = (EPI == 3) ? (bz ? F1 : F0) : nullptr;

#pragma unroll
  for (int m = 0; m < FM; ++m) {
    const int grow0 = bm0 + (m / HM) * (BM / 2) + wr * (RM / 2) +
                      (m % HM) * 16 + khi * 4;
    if constexpr (EPI == 0) {
      float g[4];
#pragma unroll
      for (int r = 0; r < 4; ++r)
        g[r] = gates[(size_t)(grow0 + r) * NEXP + ecol];
#pragma unroll
      for (int n = 0; n < FN; ++n) {
        const int gcol = bn0 + (n / HN) * (BN / 2) + wc * (RN / 2) +
                         (n % HN) * 16 + lrow;
        const float bv = bias[gcol];
        f32x4 a = acc[m][n];
#pragma unroll
        for (int r = 0; r < 4; ++r) {
          float v = a[r] + bv;
          v = v > 0.f ? v : 0.f;
          Hp[(size_t)(grow0 + r) * ldo + gcol] = (__bf16)(v * g[r]);
        }
      }
    } else {
#pragma unroll
      for (int n = 0; n < FN; ++n) {
        const int gcol = bn0 + (n / HN) * (BN / 2) + wc * (RN / 2) +
                         (n % HN) * 16 + lrow;
        f32x4 a = acc[m][n];
#pragma unroll
        for (int r = 0; r < 4; ++r) {
          float* o = F + (size_t)(grow0 + r) * N + gcol;
          if (first) *o = a[r];
          else       *o += a[r];
        }
      }
    }
  }
}

// ---------------------------------------------------------------------------
extern "C" void kernel_launch(void* const* d_in, const int* in_sizes, int n_in,
                              void* d_out, int out_size, void* d_ws, size_t ws_size,
                              hipStream_t stream) {
  const float* x  = (const float*)d_in[0];
  const float* W1 = (const float*)d_in[1];
  const float* b1 = (const float*)d_in[2];
  const float* W2 = (const float*)d_in[3];
  const float* b2 = (const float*)d_in[4];
  const float* Wg = (const float*)d_in[5];
  const float* bg = (const float*)d_in[6];
  float* out = (float*)d_out;

  // ws layout
  char* w = (char*)d_ws;
  float* gates = (float*)w;   w += (size_t)TOKENS * NEXP * 4;       //   0.25 MB
  __bf16* xb   = (__bf16*)w;  w += (size_t)TOKENS * D_IN * 2;       //  16 MB
  __bf16* w1t  = (__bf16*)w;  w += (size_t)NEXP * HDIM * D_IN * 2;  //  32 MB
  __bf16* w2c  = (__bf16*)w;  w += (size_t)NEXP * D_OUT * HDIM * 2; //  32 MB
  const size_t base = (size_t)(w - (char*)d_ws);

  const size_t acc_b = (size_t)TOKENS * D_OUT * 4;  // 32 MB
  const size_t h1_b  = (size_t)TOKENS * HDIM * 2;   // 32 MB per expert
  const int G = (ws_size >= base + acc_b + 4 * h1_b) ? 4
              : (ws_size >= base + acc_b + 2 * h1_b) ? 2 : 1;

  float* acc1 = nullptr;
  if (G > 1) { acc1 = (float*)w; w += acc_b; }
  __bf16* hbuf = (__bf16*)w;

  const size_t WSLICE = (size_t)HDIM * D_IN;   // w1t per-expert elems

  gate_cvt_kernel<<<TOKENS / 4, 256, 0, stream>>>(x, Wg, bg, gates, xb);
  transpose_cvt_kernel<<<dim3(HDIM / 32, D_IN / 32, NEXP), 256, 0, stream>>>(
      W1, w1t, D_IN, HDIM, 1);
  transpose_cvt_kernel<<<dim3(D_OUT / 32, HDIM / 32, NEXP), 256, 0, stream>>>(
      W2, w2c, HDIM, D_OUT, (G == 4) ? 2 : 1);

  if (G == 4) {
    // hbuf: 2 slices x [TOKENS][4096]; slice i2 holds experts {4d+2*i2, +1}
    for (int d = 0; d < 2; ++d) {
      for (int i2 = 0; i2 < 2; ++i2) {
        const int e0 = 4 * d + 2 * i2;
        moe_gemm<512, 256, 256, 2, 4, 0, 1><<<dim3(8, 32, 2), 512, 0, stream>>>(
            xb, 0, w1t + (size_t)e0 * WSLICE, WSLICE, b1, gates, e0,
            hbuf + (size_t)i2 * TOKENS * 4096, 0, HDIM, 2 * HDIM,
            nullptr, nullptr, 0, TOKENS, HDIM, D_IN);
      }
      // GEMM2: reg-staged coalesced pipeline; z = parity slice
      moe_gemm<512, 256, 256, 2, 4, 3, 3><<<dim3(4, 32, 2), 512, 0, stream>>>(
          hbuf, (size_t)TOKENS * 4096,
          w2c + (size_t)(2 * d) * D_OUT * 4096, (size_t)D_OUT * 4096,
          nullptr, nullptr, 0, nullptr, 0, 0, 0,
          out, acc1, (d == 0) ? 1 : 0, TOKENS, D_OUT, 2 * HDIM);
    }
  } else if (G == 2) {
    // hbuf: 2 slices x [TOKENS][2048]; slice z holds expert 2d+z
    for (int d = 0; d < 4; ++d) {
      const int e0 = 2 * d;
      moe_gemm<512, 256, 256, 2, 4, 0, 1><<<dim3(8, 32, 2), 512, 0, stream>>>(
          xb, 0, w1t + (size_t)e0 * WSLICE, WSLICE, b1, gates, e0,
          hbuf, (size_t)TOKENS * HDIM, 0, HDIM,
          nullptr, nullptr, 0, TOKENS, HDIM, D_IN);
      moe_gemm<512, 256, 256, 2, 4, 3, 3><<<dim3(4, 32, 2), 512, 0, stream>>>(
          hbuf, (size_t)TOKENS * HDIM,
          w2c + (size_t)e0 * D_OUT * HDIM, (size_t)D_OUT * HDIM,
          nullptr, nullptr, 0, nullptr, 0, 0, 0,
          out, acc1, (d == 0) ? 1 : 0, TOKENS, D_OUT, HDIM);
    }
  } else {
    // G1 fallback: single expert at a time
    for (int e = 0; e < NEXP; ++e) {
      moe_gemm<512, 256, 256, 2, 4, 0, 1><<<dim3(8, 32, 1), 512, 0, stream>>>(
          xb, 0, w1t + (size_t)e * WSLICE, 0, b1, gates, e,
          hbuf, 0, 0, HDIM,
          nullptr, nullptr, 0, TOKENS, HDIM, D_IN);
      moe_gemm<512, 256, 256, 2, 4, 3, 3><<<dim3(4, 32, 1), 512, 0, stream>>>(
          hbuf, 0, w2c + (size_t)e * D_OUT * HDIM, 0,
          nullptr, nullptr, 0, nullptr, 0, 0, 0,
          out, nullptr, (e == 0) ? 1 : 0, TOKENS, D_OUT, HDIM);
    }
  }

  merge_kernel<<<TOKENS, 256, 0, stream>>>(out, acc1, gates, b2, (G > 1) ? 1 : 0);
}

// Round 15
// 1403.591 us; speedup vs baseline: 1.2670x; 1.2670x over previous
//
#include <hip/hip_runtime.h>
#include <stdint.h>

// Problem constants (fixed by the reference)
#define TOKENS 8192
#define D_IN   1024
#define NEXP   8
#define D_OUT  1024
#define HDIM   2048

typedef __bf16 bf16x8 __attribute__((ext_vector_type(8)));
typedef __bf16 bf16x4 __attribute__((ext_vector_type(4)));
typedef float  f32x4  __attribute__((ext_vector_type(4)));

// ---------------------------------------------------------------------------
__device__ __forceinline__ void gload16(const void* g, void* l) {
  __builtin_amdgcn_global_load_lds(
      (const __attribute__((address_space(1))) void*)g,
      (__attribute__((address_space(3))) void*)l,
      16, 0, 0);
}

template <int N>
__device__ __forceinline__ void waitv() {
  if constexpr (N == 0)      asm volatile("s_waitcnt vmcnt(0)" ::: "memory");
  else if constexpr (N == 1) asm volatile("s_waitcnt vmcnt(1)" ::: "memory");
  else if constexpr (N == 2) asm volatile("s_waitcnt vmcnt(2)" ::: "memory");
  else if constexpr (N == 4) asm volatile("s_waitcnt vmcnt(4)" ::: "memory");
  else if constexpr (N == 8) asm volatile("s_waitcnt vmcnt(8)" ::: "memory");
  else static_assert(N <= 8, "unsupported vmcnt");
}

// ---------------------------------------------------------------------------
// Fused gating + x->bf16 conversion. One wave per token.
__global__ void gate_cvt_kernel(const float* __restrict__ x,
                                const float* __restrict__ Wg,
                                const float* __restrict__ bg,
                                float* __restrict__ gates,
                                __bf16* __restrict__ xb) {
  const int lane = threadIdx.x & 63;
  const int n = blockIdx.x * 4 + (threadIdx.x >> 6);
  float acc[NEXP];
#pragma unroll
  for (int e = 0; e < NEXP; ++e) acc[e] = 0.f;
  const float* xr = x + (size_t)n * D_IN;
  __bf16* xo = xb + (size_t)n * D_IN;
#pragma unroll 4
  for (int d0 = 0; d0 < D_IN; d0 += 64) {
    const int d = d0 + lane;
    float xv = xr[d];
    xo[d] = (__bf16)xv;
    const float* wr = Wg + d * NEXP;
#pragma unroll
    for (int e = 0; e < NEXP; ++e) acc[e] += xv * wr[e];
  }
#pragma unroll
  for (int e = 0; e < NEXP; ++e) {
    float v = acc[e];
#pragma unroll
    for (int off = 32; off > 0; off >>= 1) v += __shfl_down(v, off);
    acc[e] = v;
  }
  if (lane == 0) {
    float mx = -1e30f;
#pragma unroll
    for (int e = 0; e < NEXP; ++e) { acc[e] += bg[e]; mx = fmaxf(mx, acc[e]); }
    float s = 0.f;
#pragma unroll
    for (int e = 0; e < NEXP; ++e) { acc[e] = expf(acc[e] - mx); s += acc[e]; }
    float inv = 1.f / s;
#pragma unroll
    for (int e = 0; e < NEXP; ++e) gates[n * NEXP + e] = acc[e] * inv;
  }
}

// ---------------------------------------------------------------------------
// Transpose-convert: f32 W[e][k][n] -> bf16 Wt[slice = e/EPG][n][(e%EPG)*K + k]
__global__ void transpose_cvt_kernel(const float* __restrict__ W,
                                     __bf16* __restrict__ Wt,
                                     int K, int N, int EPG) {
  __shared__ float tile[32][33];
  const int e = blockIdx.z;
  const int ldo = EPG * K;
  const float* Win = W + (size_t)e * K * N;
  __bf16* Wout = Wt + (size_t)(e / EPG) * N * ldo + (size_t)(e % EPG) * K;
  const int n0 = blockIdx.x * 32;
  const int k0 = blockIdx.y * 32;
  const int tx = threadIdx.x & 31;
  const int ty = threadIdx.x >> 5;
#pragma unroll
  for (int r = ty; r < 32; r += 8)
    tile[r][tx] = Win[(size_t)(k0 + r) * N + n0 + tx];
  __syncthreads();
#pragma unroll
  for (int r = ty; r < 32; r += 8)
    Wout[(size_t)(n0 + r) * ldo + k0 + tx] = (__bf16)tile[tx][r];
}

// ---------------------------------------------------------------------------
// Final merge: out[n][f] += (use_acc1 ? acc1[n][f] : 0) + sum_e g[n][e]*b2[e][f]
__global__ void merge_kernel(float* __restrict__ out,
                             const float* __restrict__ acc1,
                             const float* __restrict__ gates,
                             const float* __restrict__ b2,
                             int use_acc1) {
  const int idx = blockIdx.x * 256 + threadIdx.x;   // over TOKENS*D_OUT/4
  const int n = idx >> 8;
  const int fb = idx & 255;
  float4 o = ((const float4*)out)[idx];
  if (use_acc1) {
    float4 a = ((const float4*)acc1)[idx];
    o.x += a.x; o.y += a.y; o.z += a.z; o.w += a.w;
  }
  const float* g = gates + (size_t)n * NEXP;
#pragma unroll
  for (int e = 0; e < NEXP; ++e) {
    const float ge = g[e];
    float4 b = ((const float4*)(b2 + (size_t)e * D_OUT))[fb];
    o.x += ge * b.x; o.y += ge * b.y; o.z += ge * b.z; o.w += ge * b.w;
  }
  ((float4*)out)[idx] = o;
}

// ---------------------------------------------------------------------------
// Rotating GEMM: D = A[M][K]*B[N][K]^T, bf16, f32 accum. BK=64, XOR swizzle
// (row&7)<<4 on LDS layout. Per-wave tile 128x64.
//
// DBUF=1 (R8-verified): gload_lds staging (pre-swizzled source), one slot,
//   4 phases/K-tile, counted vmcnt.
// DBUF=4 (NEW): hybrid coalesced staging. A (HBM stream) is reg-staged with
//   LINEAR lane addresses via NAMED registers (no address-taken arrays — the
//   R14 pointer-lambda version scratch-spilled 4 MB/block) then ds_write to
//   swizzled LDS. B (small, L2-resident) keeps gload_lds. 2 slots, 2
//   barriers/K-tile, 32-MFMA clusters. Per iter t (slot s=t&1):
//     p0: rd A0 + all B (ds) ; issue A(t+2)->regs ; lgkm0 ; BAR ;
//         gldsB(t+2)->slot s ; 32-MFMA (m-half0)
//     p1: rd A1 (ds) ; vmcnt(8) [A(t+1) regs + B(t+1) lds landed] ;
//         ds_write A(t+1)->slot s^1 ; lgkm0 ; 32-MFMA (m-half1) ; BAR
//   FIFO: queue 8->16->8; steady wait vmcnt(8), never 0 mid-loop.
//   Races: gldsB into slot s only after p0 BAR (all waves read B(t));
//   WSTAGEA into s^1 one full iter after its last reader (end BARs);
//   lgkm0 precedes the BAR that publishes ds_writes.
// z-dim: A += z*AZ, B += z*BZ.
// EPI 0 (GEMM1): Hout[row][z*OCZ+col] = bf16(relu(D+b1[e0+z][col])*g[row][e0+z])
// EPI 3 (GEMM2): F = (z ? F1 : F0); F[row][col] (first ? = : +=) D.
template <int NT, int BM, int BN, int WM, int WN, int EPI, int DBUF>
__global__ __launch_bounds__(NT, 2)
void moe_gemm(const __bf16* __restrict__ A, size_t AZ,
              const __bf16* __restrict__ B, size_t BZ,
              const float* __restrict__ b1g,
              const float* __restrict__ gates,
              int e0,
              __bf16* __restrict__ Hout, size_t HZ, int OCZ, int ldo,
              float* __restrict__ F0, float* __restrict__ F1,
              int first, int M, int N, int K) {
  constexpr int RM = BM / WM, RN = BN / WN;
  constexpr int FM = RM / 16, FN = RN / 16;
  constexpr int HM = FM / 2,  HN = FN / 2;
  constexpr int LA = BM * 4 / NT;       // loads/thread per A-half
  constexpr int LB = BN * 4 / NT;       // loads/thread per B-half
  constexpr int AELEM = BM * 64;        // A region elems per slot
  constexpr int SLOT  = (BM + BN) * 64; // elems per slot
  constexpr int NSLOT = (DBUF == 1) ? 1 : 2;
  static_assert(HM * HN * 2 == 16, "want 16-MFMA quadrant clusters");
  __shared__ alignas(16) __bf16 lds[NSLOT * SLOT];

  const int tid  = threadIdx.x;
  const int lane = tid & 63;
  const int wave = tid >> 6;
  const int wr   = wave / WN;
  const int wc   = wave % WN;
  const int lrow = lane & 15;
  const int khi  = lane >> 4;
  const int sx   = (lrow & 7) << 3;     // read-side swizzle (elements)
  const int bz   = blockIdx.z;

  A += (size_t)bz * AZ;
  B += (size_t)bz * BZ;

  // XCD-aware bijective block swizzle (per-z nwg divisible by 8)
  const int Gx   = gridDim.x;
  const int nwg  = Gx * gridDim.y;
  const int orig = blockIdx.y * Gx + blockIdx.x;
  const int wgid = (orig & 7) * (nwg >> 3) + (orig >> 3);
  const int bn0  = (wgid % Gx) * BN;
  const int bm0  = (wgid / Gx) * BM;

  f32x4 acc[FM][FN];
#pragma unroll
  for (int m = 0; m < FM; ++m)
#pragma unroll
    for (int n = 0; n < FN; ++n) acc[m][n] = f32x4{0.f, 0.f, 0.f, 0.f};

  bf16x8 af[HM][2];       // current mq-half A fragments
  bf16x8 bf[2][HN][2];    // B fragments, cached across the K-tile

  auto rdA = [&](const __bf16* As, int mq) {
#pragma unroll
    for (int mi = 0; mi < HM; ++mi)
#pragma unroll
      for (int kk = 0; kk < 2; ++kk)
        af[mi][kk] = *(const bf16x8*)
            &As[(size_t)(mq * (BM / 2) + wr * (RM / 2) + mi * 16 + lrow) * 64 +
                ((kk * 32 + khi * 8) ^ sx)];
  };
  auto rdB = [&](const __bf16* Bs, int nq) {
#pragma unroll
    for (int ni = 0; ni < HN; ++ni)
#pragma unroll
      for (int kk = 0; kk < 2; ++kk)
        bf[nq][ni][kk] = *(const bf16x8*)
            &Bs[(size_t)(nq * (BN / 2) + wc * (RN / 2) + ni * 16 + lrow) * 64 +
                ((kk * 32 + khi * 8) ^ sx)];
  };
  // 16-MFMA quadrant cluster (DBUF=1)
  auto cluster = [&](int mq, int nq) {
    __builtin_amdgcn_s_setprio(1);
#pragma unroll
    for (int kk = 0; kk < 2; ++kk)
#pragma unroll
      for (int mi = 0; mi < HM; ++mi)
#pragma unroll
        for (int ni = 0; ni < HN; ++ni)
          acc[mq * HM + mi][nq * HN + ni] =
              __builtin_amdgcn_mfma_f32_16x16x32_bf16(
                  af[mi][kk], bf[nq][ni][kk], acc[mq * HM + mi][nq * HN + ni],
                  0, 0, 0);
    __builtin_amdgcn_s_setprio(0);
  };
  // 32-MFMA half cluster: m-half mq x ALL n (DBUF=4)
  auto cluster_h = [&](int mq) {
    __builtin_amdgcn_s_setprio(1);
#pragma unroll
    for (int kk = 0; kk < 2; ++kk)
#pragma unroll
      for (int mi = 0; mi < HM; ++mi)
#pragma unroll
        for (int nq = 0; nq < 2; ++nq)
#pragma unroll
          for (int ni = 0; ni < HN; ++ni)
            acc[mq * HM + mi][nq * HN + ni] =
                __builtin_amdgcn_mfma_f32_16x16x32_bf16(
                    af[mi][kk], bf[nq][ni][kk], acc[mq * HM + mi][nq * HN + ni],
                    0, 0, 0);
    __builtin_amdgcn_s_setprio(0);
  };

#define BAR()   asm volatile("s_barrier" ::: "memory")
#define LGKM0() do { asm volatile("s_waitcnt lgkmcnt(0)" ::: "memory"); \
                     __builtin_amdgcn_sched_barrier(0); } while (0)

  const int nk = K >> 6;

  if constexpr (DBUF == 1) {
    // ---- R8-verified single-slot 4-phase schedule (gload_lds staging) ----
    const __bf16* srcA[2][LA];
    const __bf16* srcB[2][LB];
#pragma unroll
    for (int q = 0; q < 2; ++q) {
#pragma unroll
      for (int j = 0; j < LA; ++j) {
        int o   = q * (BM * 64) + j * (NT * 16) + tid * 16;
        int row = o >> 7;
        int cb  = (o & 127) ^ ((row & 7) << 4);
        srcA[q][j] = A + (size_t)(bm0 + row) * K + (cb >> 1);
      }
#pragma unroll
      for (int j = 0; j < LB; ++j) {
        int o   = q * (BN * 64) + j * (NT * 16) + tid * 16;
        int row = o >> 7;
        int cb  = (o & 127) ^ ((row & 7) << 4);
        srcB[q][j] = B + (size_t)(bn0 + row) * K + (cb >> 1);
      }
    }
    auto stageA = [&](int kt, int q) {
#pragma unroll
      for (int j = 0; j < LA; ++j)
        gload16(srcA[q][j] + (size_t)kt * 64,
                lds + q * (BM * 32) + j * (NT * 8) + wave * 512);
    };
    auto stageB = [&](int kt, int q) {
#pragma unroll
      for (int j = 0; j < LB; ++j)
        gload16(srcB[q][j] + (size_t)kt * 64,
                lds + AELEM + q * (BN * 32) + j * (NT * 8) + wave * 512);
    };

    stageA(0, 0); stageB(0, 0); stageB(0, 1);
    waitv<LB>();
    BAR();
    for (int t = 0; t < nk; ++t) {
      const bool pf = (t + 1 < nk);
      rdA(lds, 0); rdB(lds + AELEM, 0);
      stageA(t, 1);
      BAR(); LGKM0();
      cluster(0, 0);
      waitv<LA>();
      BAR();
      rdB(lds + AELEM, 1);
      if (pf) stageA(t + 1, 0);
      BAR(); LGKM0();
      cluster(0, 1);
      if (pf) waitv<LA>(); else waitv<0>();
      BAR();
      rdA(lds, 1);
      if (pf) stageB(t + 1, 0);
      BAR(); LGKM0();
      cluster(1, 0);
      BAR();
      if (pf) stageB(t + 1, 1);
      BAR();
      cluster(1, 1);
      if (pf) waitv<LB>();
      BAR();
    }
  } else {
    // ---- DBUF=4: hybrid coalesced staging (A reg-staged, B gload_lds) ----
    static_assert(LA == 2 && LB == 2, "DBUF=4 sized for 256x256 @512 thr");
    // A: LINEAR sources (coalesced) + swizzled LDS dest byte offsets.
    const __bf16* srcLinA[4];
    int dstSwzA[4];
#pragma unroll
    for (int i = 0; i < 4; ++i) {
      int o   = i * (NT * 16) + tid * 16;     // A region byte offset (linear)
      int row = o >> 7;
      int colb = o & 127;
      srcLinA[i] = A + (size_t)(bm0 + row) * K + (colb >> 1);
      dstSwzA[i] = (o & ~127) | (colb ^ ((row & 7) << 4));
    }
    // B: pre-swizzled gload_lds sources (as DBUF=1)
    const __bf16* srcB[2][LB];
#pragma unroll
    for (int q = 0; q < 2; ++q)
#pragma unroll
      for (int j = 0; j < LB; ++j) {
        int o   = q * (BN * 64) + j * (NT * 16) + tid * 16;
        int row = o >> 7;
        int cb  = (o & 127) ^ ((row & 7) << 4);
        srcB[q][j] = B + (size_t)(bn0 + row) * K + (cb >> 1);
      }
    auto stageB2 = [&](int kt, int s) {
#pragma unroll
      for (int q = 0; q < 2; ++q)
#pragma unroll
        for (int j = 0; j < LB; ++j)
          gload16(srcB[q][j] + (size_t)kt * 64,
                  lds + s * SLOT + AELEM + q * (BN * 32) + j * (NT * 8) +
                      wave * 512);
    };

    // Named staging registers (NO address-taken arrays — avoids scratch).
    float4 RAa0, RAa1, RAa2, RAa3, RAb0, RAb1, RAb2, RAb3;
#define ISSUEA(kt, S)                                                          \
  do {                                                                         \
    S##0 = *reinterpret_cast<const float4*>(srcLinA[0] + (size_t)(kt) * 64);   \
    S##1 = *reinterpret_cast<const float4*>(srcLinA[1] + (size_t)(kt) * 64);   \
    S##2 = *reinterpret_cast<const float4*>(srcLinA[2] + (size_t)(kt) * 64);   \
    S##3 = *reinterpret_cast<const float4*>(srcLinA[3] + (size_t)(kt) * 64);   \
  } while (0)
#define WSTAGEA(sbyte, S)                                                      \
  do {                                                                         \
    char* b_ = (char*)lds + (sbyte);                                           \
    *reinterpret_cast<float4*>(b_ + dstSwzA[0]) = S##0;                        \
    *reinterpret_cast<float4*>(b_ + dstSwzA[1]) = S##1;                        \
    *reinterpret_cast<float4*>(b_ + dstSwzA[2]) = S##2;                        \
    *reinterpret_cast<float4*>(b_ + dstSwzA[3]) = S##3;                        \
  } while (0)

    // prologue: A(0)->RAa, B(0)->slot0, A(1)->RAb, B(1)->slot1
    ISSUEA(0, RAa);
    stageB2(0, 0);
    ISSUEA(1, RAb);
    stageB2(1, 1);
    waitv<8>();            // A(0) regs + B(0) lds landed; A(1),B(1) in flight
    WSTAGEA(0, RAa);       // write A(0) -> slot 0
    LGKM0();
    BAR();                 // slot 0 published

    const int half = nk >> 1;   // nk even for all our K
    for (int tt = 0; tt < half; ++tt) {
      {  // ---- even tile t = 2tt, slot 0 : issue->RAa, write RAb(A(t+1))
        const int t = 2 * tt;
        const __bf16* As = lds;
        const __bf16* Bs = lds + AELEM;
        const bool pf2 = (t + 2 < nk);
        const bool pf1 = (t + 1 < nk);
        rdA(As, 0); rdB(Bs, 0); rdB(Bs, 1);
        if (pf2) ISSUEA(t + 2, RAa);
        LGKM0();
        BAR();                       // all waves done reading B(t),A0(t)
        if (pf2) stageB2(t + 2, 0);  // B(t+2) -> slot 0 B-region
        cluster_h(0);
        rdA(As, 1);
        if (pf2) waitv<8>(); else if (pf1) waitv<0>();
        if (pf1) WSTAGEA(SLOT * 2, RAb);   // A(t+1) -> slot 1
        LGKM0();
        cluster_h(1);
        BAR();                       // publish slot 1
      }
      {  // ---- odd tile t = 2tt+1, slot 1 : issue->RAb, write RAa(A(t+1))
        const int t = 2 * tt + 1;
        const __bf16* As = lds + SLOT;
        const __bf16* Bs = As + AELEM;
        const bool pf2 = (t + 2 < nk);
        const bool pf1 = (t + 1 < nk);
        rdA(As, 0); rdB(Bs, 0); rdB(Bs, 1);
        if (pf2) ISSUEA(t + 2, RAb);
        LGKM0();
        BAR();
        if (pf2) stageB2(t + 2, 1);  // B(t+2) -> slot 1 B-region
        cluster_h(0);
        rdA(As, 1);
        if (pf2) waitv<8>(); else if (pf1) waitv<0>();
        if (pf1) WSTAGEA(0, RAa);    // A(t+1) -> slot 0
        LGKM0();
        cluster_h(1);
        BAR();                       // publish slot 0
      }
    }
#undef ISSUEA
#undef WSTAGEA
  }

#undef BAR
#undef LGKM0

  // Epilogue. C/D frag: col = lane&15, row = (lane>>4)*4 + reg  [HW-verified]
  const float* bias = (EPI == 0) ? b1g + (size_t)(e0 + bz) * HDIM : nullptr;
  const int ecol = e0 + bz;
  __bf16* Hp = (EPI == 0) ? Hout + (size_t)bz * HZ + (size_t)bz * OCZ : nullptr;
  float* F = (EPI == 3) ? (bz ? F1 : F0) : nullptr;

#pragma unroll
  for (int m = 0; m < FM; ++m) {
    const int grow0 = bm0 + (m / HM) * (BM / 2) + wr * (RM / 2) +
                      (m % HM) * 16 + khi * 4;
    if constexpr (EPI == 0) {
      float g[4];
#pragma unroll
      for (int r = 0; r < 4; ++r)
        g[r] = gates[(size_t)(grow0 + r) * NEXP + ecol];
#pragma unroll
      for (int n = 0; n < FN; ++n) {
        const int gcol = bn0 + (n / HN) * (BN / 2) + wc * (RN / 2) +
                         (n % HN) * 16 + lrow;
        const float bv = bias[gcol];
        f32x4 a = acc[m][n];
#pragma unroll
        for (int r = 0; r < 4; ++r) {
          float v = a[r] + bv;
          v = v > 0.f ? v : 0.f;
          Hp[(size_t)(grow0 + r) * ldo + gcol] = (__bf16)(v * g[r]);
        }
      }
    } else {
#pragma unroll
      for (int n = 0; n < FN; ++n) {
        const int gcol = bn0 + (n / HN) * (BN / 2) + wc * (RN / 2) +
                         (n % HN) * 16 + lrow;
        f32x4 a = acc[m][n];
#pragma unroll
        for (int r = 0; r < 4; ++r) {
          float* o = F + (size_t)(grow0 + r) * N + gcol;
          if (first) *o = a[r];
          else       *o += a[r];
        }
      }
    }
  }
}

// ---------------------------------------------------------------------------
extern "C" void kernel_launch(void* const* d_in, const int* in_sizes, int n_in,
                              void* d_out, int out_size, void* d_ws, size_t ws_size,
                              hipStream_t stream) {
  const float* x  = (const float*)d_in[0];
  const float* W1 = (const float*)d_in[1];
  const float* b1 = (const float*)d_in[2];
  const float* W2 = (const float*)d_in[3];
  const float* b2 = (const float*)d_in[4];
  const float* Wg = (const float*)d_in[5];
  const float* bg = (const float*)d_in[6];
  float* out = (float*)d_out;

  // ws layout
  char* w = (char*)d_ws;
  float* gates = (float*)w;   w += (size_t)TOKENS * NEXP * 4;       //   0.25 MB
  __bf16* xb   = (__bf16*)w;  w += (size_t)TOKENS * D_IN * 2;       //  16 MB
  __bf16* w1t  = (__bf16*)w;  w += (size_t)NEXP * HDIM * D_IN * 2;  //  32 MB
  __bf16* w2c  = (__bf16*)w;  w += (size_t)NEXP * D_OUT * HDIM * 2; //  32 MB
  const size_t base = (size_t)(w - (char*)d_ws);

  const size_t acc_b = (size_t)TOKENS * D_OUT * 4;  // 32 MB
  const size_t h1_b  = (size_t)TOKENS * HDIM * 2;   // 32 MB per expert
  const int G = (ws_size >= base + acc_b + 4 * h1_b) ? 4
              : (ws_size >= base + acc_b + 2 * h1_b) ? 2 : 1;

  float* acc1 = nullptr;
  if (G > 1) { acc1 = (float*)w; w += acc_b; }
  __bf16* hbuf = (__bf16*)w;

  const size_t WSLICE = (size_t)HDIM * D_IN;   // w1t per-expert elems

  gate_cvt_kernel<<<TOKENS / 4, 256, 0, stream>>>(x, Wg, bg, gates, xb);
  transpose_cvt_kernel<<<dim3(HDIM / 32, D_IN / 32, NEXP), 256, 0, stream>>>(
      W1, w1t, D_IN, HDIM, 1);
  transpose_cvt_kernel<<<dim3(D_OUT / 32, HDIM / 32, NEXP), 256, 0, stream>>>(
      W2, w2c, HDIM, D_OUT, (G == 4) ? 2 : 1);

  if (G == 4) {
    // hbuf: 2 slices x [TOKENS][4096]; slice i2 holds experts {4d+2*i2, +1}
    for (int d = 0; d < 2; ++d) {
      for (int i2 = 0; i2 < 2; ++i2) {
        const int e0 = 4 * d + 2 * i2;
        moe_gemm<512, 256, 256, 2, 4, 0, 1><<<dim3(8, 32, 2), 512, 0, stream>>>(
            xb, 0, w1t + (size_t)e0 * WSLICE, WSLICE, b1, gates, e0,
            hbuf + (size_t)i2 * TOKENS * 4096, 0, HDIM, 2 * HDIM,
            nullptr, nullptr, 0, TOKENS, HDIM, D_IN);
      }
      // GEMM2: hybrid coalesced pipeline; z = parity slice
      moe_gemm<512, 256, 256, 2, 4, 3, 4><<<dim3(4, 32, 2), 512, 0, stream>>>(
          hbuf, (size_t)TOKENS * 4096,
          w2c + (size_t)(2 * d) * D_OUT * 4096, (size_t)D_OUT * 4096,
          nullptr, nullptr, 0, nullptr, 0, 0, 0,
          out, acc1, (d == 0) ? 1 : 0, TOKENS, D_OUT, 2 * HDIM);
    }
  } else if (G == 2) {
    // hbuf: 2 slices x [TOKENS][2048]; slice z holds expert 2d+z
    for (int d = 0; d < 4; ++d) {
      const int e0 = 2 * d;
      moe_gemm<512, 256, 256, 2, 4, 0, 1><<<dim3(8, 32, 2), 512, 0, stream>>>(
          xb, 0, w1t + (size_t)e0 * WSLICE, WSLICE, b1, gates, e0,
          hbuf, (size_t)TOKENS * HDIM, 0, HDIM,
          nullptr, nullptr, 0, TOKENS, HDIM, D_IN);
      moe_gemm<512, 256, 256, 2, 4, 3, 4><<<dim3(4, 32, 2), 512, 0, stream>>>(
          hbuf, (size_t)TOKENS * HDIM,
          w2c + (size_t)e0 * D_OUT * HDIM, (size_t)D_OUT * HDIM,
          nullptr, nullptr, 0, nullptr, 0, 0, 0,
          out, acc1, (d == 0) ? 1 : 0, TOKENS, D_OUT, HDIM);
    }
  } else {
    // G1 fallback: single expert at a time
    for (int e = 0; e < NEXP; ++e) {
      moe_gemm<512, 256, 256, 2, 4, 0, 1><<<dim3(8, 32, 1), 512, 0, stream>>>(
          xb, 0, w1t + (size_t)e * WSLICE, 0, b1, gates, e,
          hbuf, 0, 0, HDIM,
          nullptr, nullptr, 0, TOKENS, HDIM, D_IN);
      moe_gemm<512, 256, 256, 2, 4, 3, 4><<<dim3(4, 32, 1), 512, 0, stream>>>(
          hbuf, 0, w2c + (size_t)e * D_OUT * HDIM, 0,
          nullptr, nullptr, 0, nullptr, 0, 0, 0,
          out, nullptr, (e == 0) ? 1 : 0, TOKENS, D_OUT, HDIM);
    }
  }

  merge_kernel<<<TOKENS, 256, 0, stream>>>(out, acc1, gates, b2, (G > 1) ? 1 : 0);
}

// Round 16
// 645.535 us; speedup vs baseline: 2.7549x; 2.1743x over previous
//
#include <hip/hip_runtime.h>
#include <stdint.h>

// Problem constants (fixed by the reference)
#define TOKENS 8192
#define D_IN   1024
#define NEXP   8
#define D_OUT  1024
#define HDIM   2048

typedef __bf16 bf16x8 __attribute__((ext_vector_type(8)));
typedef __bf16 bf16x4 __attribute__((ext_vector_type(4)));
typedef float  f32x4  __attribute__((ext_vector_type(4)));

// ---------------------------------------------------------------------------
__device__ __forceinline__ void gload16(const void* g, void* l) {
  __builtin_amdgcn_global_load_lds(
      (const __attribute__((address_space(1))) void*)g,
      (__attribute__((address_space(3))) void*)l,
      16, 0, 0);
}

template <int N>
__device__ __forceinline__ void waitv() {
  if constexpr (N == 0)      asm volatile("s_waitcnt vmcnt(0)" ::: "memory");
  else if constexpr (N == 1) asm volatile("s_waitcnt vmcnt(1)" ::: "memory");
  else if constexpr (N == 2) asm volatile("s_waitcnt vmcnt(2)" ::: "memory");
  else if constexpr (N == 3) asm volatile("s_waitcnt vmcnt(3)" ::: "memory");
  else if constexpr (N == 4) asm volatile("s_waitcnt vmcnt(4)" ::: "memory");
  else static_assert(N <= 4, "unsupported vmcnt");
}

// ---------------------------------------------------------------------------
// Fused gating + x->bf16 conversion. One wave per token.
__global__ void gate_cvt_kernel(const float* __restrict__ x,
                                const float* __restrict__ Wg,
                                const float* __restrict__ bg,
                                float* __restrict__ gates,
                                __bf16* __restrict__ xb) {
  const int lane = threadIdx.x & 63;
  const int n = blockIdx.x * 4 + (threadIdx.x >> 6);
  float acc[NEXP];
#pragma unroll
  for (int e = 0; e < NEXP; ++e) acc[e] = 0.f;
  const float* xr = x + (size_t)n * D_IN;
  __bf16* xo = xb + (size_t)n * D_IN;
#pragma unroll 4
  for (int d0 = 0; d0 < D_IN; d0 += 64) {
    const int d = d0 + lane;
    float xv = xr[d];
    xo[d] = (__bf16)xv;
    const float* wr = Wg + d * NEXP;
#pragma unroll
    for (int e = 0; e < NEXP; ++e) acc[e] += xv * wr[e];
  }
#pragma unroll
  for (int e = 0; e < NEXP; ++e) {
    float v = acc[e];
#pragma unroll
    for (int off = 32; off > 0; off >>= 1) v += __shfl_down(v, off);
    acc[e] = v;
  }
  if (lane == 0) {
    float mx = -1e30f;
#pragma unroll
    for (int e = 0; e < NEXP; ++e) { acc[e] += bg[e]; mx = fmaxf(mx, acc[e]); }
    float s = 0.f;
#pragma unroll
    for (int e = 0; e < NEXP; ++e) { acc[e] = expf(acc[e] - mx); s += acc[e]; }
    float inv = 1.f / s;
#pragma unroll
    for (int e = 0; e < NEXP; ++e) gates[n * NEXP + e] = acc[e] * inv;
  }
}

// ---------------------------------------------------------------------------
// Transpose-convert: f32 W[e][k][n] -> bf16 Wt[slice = e/EPG][n][(e%EPG)*K + k]
__global__ void transpose_cvt_kernel(const float* __restrict__ W,
                                     __bf16* __restrict__ Wt,
                                     int K, int N, int EPG) {
  __shared__ float tile[32][33];
  const int e = blockIdx.z;
  const int ldo = EPG * K;
  const float* Win = W + (size_t)e * K * N;
  __bf16* Wout = Wt + (size_t)(e / EPG) * N * ldo + (size_t)(e % EPG) * K;
  const int n0 = blockIdx.x * 32;
  const int k0 = blockIdx.y * 32;
  const int tx = threadIdx.x & 31;
  const int ty = threadIdx.x >> 5;
#pragma unroll
  for (int r = ty; r < 32; r += 8)
    tile[r][tx] = Win[(size_t)(k0 + r) * N + n0 + tx];
  __syncthreads();
#pragma unroll
  for (int r = ty; r < 32; r += 8)
    Wout[(size_t)(n0 + r) * ldo + k0 + tx] = (__bf16)tile[tx][r];
}

// ---------------------------------------------------------------------------
// Final merge: out[n][f] += sum_e g[n][e]*b2[e][f]
__global__ void merge_kernel(float* __restrict__ out,
                             const float* __restrict__ gates,
                             const float* __restrict__ b2) {
  const int idx = blockIdx.x * 256 + threadIdx.x;   // over TOKENS*D_OUT/4
  const int n = idx >> 8;
  const int fb = idx & 255;
  float4 o = ((const float4*)out)[idx];
  const float* g = gates + (size_t)n * NEXP;
#pragma unroll
  for (int e = 0; e < NEXP; ++e) {
    const float ge = g[e];
    float4 b = ((const float4*)(b2 + (size_t)e * D_OUT))[fb];
    o.x += ge * b.x; o.y += ge * b.y; o.z += ge * b.z; o.w += ge * b.w;
  }
  ((float4*)out)[idx] = o;
}

// ---------------------------------------------------------------------------
// Rotating-quarter GEMM (R8-verified schedule): D = A[M][K]*B[N][K]^T, bf16,
// f32 accum. BK=64, XOR swizzle (row&7)<<4. One LDS slot; quarters A0,B0,A1,B1
// each have ONE reader phase (p0,p0,p2,p1) and are restaged in-place 1+ phase
// after their read; counted vmcnt never 0 mid-loop:
//   p0: read A0,B0 -> mma(0,0); stage A1(t)  ; wait vmcnt(LA)  [drain B1(t)]
//   p1: read B1    -> mma(0,1); stage A0(t+1); wait vmcnt(LA|0)[drain A1(t)]
//   p2: read A1    -> mma(1,0); stage B0(t+1)
//   p3:            -> mma(1,1); stage B1(t+1); wait vmcnt(LB)  [drain A0,B0]
// Geometry templated: 8-wave 256x256 (per-wave 128x64, acc 128 AGPR, 2 w/SIMD)
// or 4-wave 128x128 (per-wave 64x64, acc 64 AGPR, ~160 regs -> 3 w/SIMD,
// 3 independent blocks/CU — the TLP lever; WPE=3 caps regs at 170).
// z-dim: A += z*AZ, B += z*BZ.
// EPI 0 (GEMM1): Hout[row][z*OCZ+col] = bf16(relu(D+b1[e0+z][col])*g[row][e0+z])
// EPI 3 (GEMM2): F0[row][col] (first ? = : +=) D.
template <int NT, int WPE, int BM, int BN, int WM, int WN, int EPI>
__global__ __launch_bounds__(NT, WPE)
void moe_gemm(const __bf16* __restrict__ A, size_t AZ,
              const __bf16* __restrict__ B, size_t BZ,
              const float* __restrict__ b1g,
              const float* __restrict__ gates,
              int e0,
              __bf16* __restrict__ Hout, int OCZ, int ldo,
              float* __restrict__ F0,
              int first, int M, int N, int K) {
  constexpr int RM = BM / WM, RN = BN / WN;
  constexpr int FM = RM / 16, FN = RN / 16;
  constexpr int HM = FM / 2,  HN = FN / 2;
  constexpr int LA = BM * 4 / NT;       // gloads/thread per A-half
  constexpr int LB = BN * 4 / NT;       // gloads/thread per B-half
  constexpr int AELEM = BM * 64;        // A region elems
  static_assert(HM >= 1 && HN >= 1, "tile too small");
  __shared__ alignas(16) __bf16 lds[(BM + BN) * 64];   // ONE slot

  const int tid  = threadIdx.x;
  const int lane = tid & 63;
  const int wave = tid >> 6;
  const int wr   = wave / WN;
  const int wc   = wave % WN;
  const int lrow = lane & 15;
  const int khi  = lane >> 4;
  const int sx   = (lrow & 7) << 3;     // read-side swizzle (elements)
  const int bz   = blockIdx.z;

  A += (size_t)bz * AZ;
  B += (size_t)bz * BZ;

  // XCD-aware bijective block swizzle (per-z nwg divisible by 8)
  const int Gx   = gridDim.x;
  const int nwg  = Gx * gridDim.y;
  const int orig = blockIdx.y * Gx + blockIdx.x;
  const int wgid = (orig & 7) * (nwg >> 3) + (orig >> 3);
  const int bn0  = (wgid % Gx) * BN;
  const int bm0  = (wgid / Gx) * BM;

  // Pre-swizzled global sources: LDS byte o of region holds global column
  // byte (o&127) ^ ((row&7)<<4) of row (o>>7).
  const __bf16* srcA[2][LA];
  const __bf16* srcB[2][LB];
#pragma unroll
  for (int q = 0; q < 2; ++q) {
#pragma unroll
    for (int j = 0; j < LA; ++j) {
      int o   = q * (BM * 64) + j * (NT * 16) + tid * 16;
      int row = o >> 7;
      int cb  = (o & 127) ^ ((row & 7) << 4);
      srcA[q][j] = A + (size_t)(bm0 + row) * K + (cb >> 1);
    }
#pragma unroll
    for (int j = 0; j < LB; ++j) {
      int o   = q * (BN * 64) + j * (NT * 16) + tid * 16;
      int row = o >> 7;
      int cb  = (o & 127) ^ ((row & 7) << 4);
      srcB[q][j] = B + (size_t)(bn0 + row) * K + (cb >> 1);
    }
  }

  auto stageA = [&](int kt, int q) {
#pragma unroll
    for (int j = 0; j < LA; ++j)
      gload16(srcA[q][j] + (size_t)kt * 64,
              lds + q * (BM * 32) + j * (NT * 8) + wave * 512);
  };
  auto stageB = [&](int kt, int q) {
#pragma unroll
    for (int j = 0; j < LB; ++j)
      gload16(srcB[q][j] + (size_t)kt * 64,
              lds + AELEM + q * (BN * 32) + j * (NT * 8) + wave * 512);
  };

  f32x4 acc[FM][FN];
#pragma unroll
  for (int m = 0; m < FM; ++m)
#pragma unroll
    for (int n = 0; n < FN; ++n) acc[m][n] = f32x4{0.f, 0.f, 0.f, 0.f};

  bf16x8 af[HM][2];       // current mq-half A fragments
  bf16x8 bf[2][HN][2];    // B fragments, cached across the K-tile

  // Fragment rows of half mq live in staged block-half mq (race-free).
  auto rdA = [&](int mq) {
#pragma unroll
    for (int mi = 0; mi < HM; ++mi)
#pragma unroll
      for (int kk = 0; kk < 2; ++kk)
        af[mi][kk] = *(const bf16x8*)
            &lds[(size_t)(mq * (BM / 2) + wr * (RM / 2) + mi * 16 + lrow) * 64 +
                 ((kk * 32 + khi * 8) ^ sx)];
  };
  auto rdB = [&](int nq) {
#pragma unroll
    for (int ni = 0; ni < HN; ++ni)
#pragma unroll
      for (int kk = 0; kk < 2; ++kk)
        bf[nq][ni][kk] = *(const bf16x8*)
            &lds[AELEM +
                 (size_t)(nq * (BN / 2) + wc * (RN / 2) + ni * 16 + lrow) * 64 +
                 ((kk * 32 + khi * 8) ^ sx)];
  };
  auto cluster = [&](int mq, int nq) {
    __builtin_amdgcn_s_setprio(1);
#pragma unroll
    for (int kk = 0; kk < 2; ++kk)
#pragma unroll
      for (int mi = 0; mi < HM; ++mi)
#pragma unroll
        for (int ni = 0; ni < HN; ++ni)
          acc[mq * HM + mi][nq * HN + ni] =
              __builtin_amdgcn_mfma_f32_16x16x32_bf16(
                  af[mi][kk], bf[nq][ni][kk], acc[mq * HM + mi][nq * HN + ni],
                  0, 0, 0);
    __builtin_amdgcn_s_setprio(0);
  };

#define BAR()   asm volatile("s_barrier" ::: "memory")
#define LGKM0() do { asm volatile("s_waitcnt lgkmcnt(0)" ::: "memory"); \
                     __builtin_amdgcn_sched_barrier(0); } while (0)

  const int nk = K >> 6;

  // prologue: stage A0(0), B0(0), B1(0); drain A0,B0 (leave B1 in flight)
  stageA(0, 0); stageB(0, 0); stageB(0, 1);
  waitv<LB>();
  BAR();

  for (int t = 0; t < nk; ++t) {
    const bool pf = (t + 1 < nk);

    // p0 : read A0,B0 ; mma(0,0) ; stage A1(t) ; drain B1(t)
    rdA(0); rdB(0);
    stageA(t, 1);
    BAR(); LGKM0();
    cluster(0, 0);
    waitv<LA>();
    BAR();
    // p1 : read B1 ; mma(0,1) ; stage A0(t+1) ; drain A1(t)
    rdB(1);
    if (pf) stageA(t + 1, 0);
    BAR(); LGKM0();
    cluster(0, 1);
    if (pf) waitv<LA>(); else waitv<0>();
    BAR();
    // p2 : read A1 ; mma(1,0) ; stage B0(t+1)
    rdA(1);
    if (pf) stageB(t + 1, 0);
    BAR(); LGKM0();
    cluster(1, 0);
    BAR();
    // p3 : mma(1,1) ; stage B1(t+1) ; drain A0,B0(t+1)
    if (pf) stageB(t + 1, 1);
    BAR();
    cluster(1, 1);
    if (pf) waitv<LB>();
    BAR();
  }

#undef BAR
#undef LGKM0

  // Epilogue. C/D frag: col = lane&15, row = (lane>>4)*4 + reg  [HW-verified]
  const float* bias = (EPI == 0) ? b1g + (size_t)(e0 + bz) * HDIM : nullptr;
  const int ecol = e0 + bz;
  __bf16* Hp = (EPI == 0) ? Hout + (size_t)bz * OCZ : nullptr;

#pragma unroll
  for (int m = 0; m < FM; ++m) {
    const int grow0 = bm0 + (m / HM) * (BM / 2) + wr * (RM / 2) +
                      (m % HM) * 16 + khi * 4;
    if constexpr (EPI == 0) {
      float g[4];
#pragma unroll
      for (int r = 0; r < 4; ++r)
        g[r] = gates[(size_t)(grow0 + r) * NEXP + ecol];
#pragma unroll
      for (int n = 0; n < FN; ++n) {
        const int gcol = bn0 + (n / HN) * (BN / 2) + wc * (RN / 2) +
                         (n % HN) * 16 + lrow;
        const float bv = bias[gcol];
        f32x4 a = acc[m][n];
#pragma unroll
        for (int r = 0; r < 4; ++r) {
          float v = a[r] + bv;
          v = v > 0.f ? v : 0.f;
          Hp[(size_t)(grow0 + r) * ldo + gcol] = (__bf16)(v * g[r]);
        }
      }
    } else {
#pragma unroll
      for (int n = 0; n < FN; ++n) {
        const int gcol = bn0 + (n / HN) * (BN / 2) + wc * (RN / 2) +
                         (n % HN) * 16 + lrow;
        f32x4 a = acc[m][n];
#pragma unroll
        for (int r = 0; r < 4; ++r) {
          float* o = F0 + (size_t)(grow0 + r) * N + gcol;
          if (first) *o = a[r];
          else       *o += a[r];
        }
      }
    }
  }
}

// ---------------------------------------------------------------------------
extern "C" void kernel_launch(void* const* d_in, const int* in_sizes, int n_in,
                              void* d_out, int out_size, void* d_ws, size_t ws_size,
                              hipStream_t stream) {
  const float* x  = (const float*)d_in[0];
  const float* W1 = (const float*)d_in[1];
  const float* b1 = (const float*)d_in[2];
  const float* W2 = (const float*)d_in[3];
  const float* b2 = (const float*)d_in[4];
  const float* Wg = (const float*)d_in[5];
  const float* bg = (const float*)d_in[6];
  float* out = (float*)d_out;

  // ws layout
  char* w = (char*)d_ws;
  float* gates = (float*)w;   w += (size_t)TOKENS * NEXP * 4;       //   0.25 MB
  __bf16* xb   = (__bf16*)w;  w += (size_t)TOKENS * D_IN * 2;       //  16 MB
  __bf16* w1t  = (__bf16*)w;  w += (size_t)NEXP * HDIM * D_IN * 2;  //  32 MB
  __bf16* w2c  = (__bf16*)w;  w += (size_t)NEXP * D_OUT * HDIM * 2; //  32 MB
  const size_t base = (size_t)(w - (char*)d_ws);

  const size_t h1_b = (size_t)TOKENS * HDIM * 2;   // 32 MB per expert
  const int G = (ws_size >= base + 4 * h1_b) ? 4
              : (ws_size >= base + 2 * h1_b) ? 2 : 1;
  __bf16* hbuf = (__bf16*)w;   // [TOKENS][G*2048] concatenated-K layout

  const size_t WSLICE = (size_t)HDIM * D_IN;   // w1t per-expert elems
  const int KB = G * HDIM;                     // GEMM2 K per group

  gate_cvt_kernel<<<TOKENS / 4, 256, 0, stream>>>(x, Wg, bg, gates, xb);
  transpose_cvt_kernel<<<dim3(HDIM / 32, D_IN / 32, NEXP), 256, 0, stream>>>(
      W1, w1t, D_IN, HDIM, 1);
  // W2: [E][H][D_OUT] -> w2c[e/G][n][(e%G)*H + k]  (LDK = G*H, matches hbuf)
  transpose_cvt_kernel<<<dim3(D_OUT / 32, HDIM / 32, NEXP), 256, 0, stream>>>(
      W2, w2c, HDIM, D_OUT, G);

  const int ngroups = NEXP / G;
  for (int d = 0; d < ngroups; ++d) {
    // GEMM1: fill hbuf[*][0..KB) with experts G*d .. G*d+G-1 (column bands)
    if (G >= 2) {
      for (int i2 = 0; i2 < G / 2; ++i2) {
        const int e0 = G * d + 2 * i2;
        moe_gemm<512, 2, 256, 256, 2, 4, 0><<<dim3(8, 32, 2), 512, 0, stream>>>(
            xb, 0, w1t + (size_t)e0 * WSLICE, WSLICE, b1, gates, e0,
            hbuf + (size_t)i2 * 2 * HDIM, HDIM, KB,
            nullptr, 0, TOKENS, HDIM, D_IN);
      }
    } else {
      moe_gemm<512, 2, 256, 256, 2, 4, 0><<<dim3(8, 32, 1), 512, 0, stream>>>(
          xb, 0, w1t + (size_t)d * WSLICE, 0, b1, gates, d,
          hbuf, 0, KB,
          nullptr, 0, TOKENS, HDIM, D_IN);
    }
    // GEMM2: 4-wave 128x128 tile, per-wave 64x64 (acc 64 AGPR -> 3 w/SIMD,
    // 3 blocks/CU); single K = G*2048 contiguous GEMM; grid 8x64 = 512 blocks
    moe_gemm<256, 3, 128, 128, 2, 2, 3><<<dim3(D_OUT / 128, TOKENS / 128, 1),
                                          256, 0, stream>>>(
        hbuf, 0, w2c + (size_t)d * D_OUT * KB, 0,
        nullptr, nullptr, 0, nullptr, 0, 0,
        out, (d == 0) ? 1 : 0, TOKENS, D_OUT, KB);
  }

  merge_kernel<<<TOKENS, 256, 0, stream>>>(out, gates, b2);
}